// Round 4
// baseline (758.728 us; speedup 1.0000x reference)
//
#include <hip/hip_runtime.h>

typedef __attribute__((ext_vector_type(8))) short bf16x8;
typedef __attribute__((ext_vector_type(4))) float f32x4;
typedef __attribute__((ext_vector_type(2))) unsigned int u32x2;
typedef __attribute__((ext_vector_type(4))) unsigned int u32x4;
typedef __attribute__((ext_vector_type(2))) __bf16 bf16x2t;
typedef unsigned short u16;
typedef unsigned int u32;

#define DI __device__ __forceinline__

// Problem constants: B=8, A=1024, NB=64, NAB=NF=128, NG=25, NI=3

DI float b2f(u16 u){ union{u32 i; float f;} v; v.i = ((u32)u)<<16; return v.f; }
DI u16 f2b(float f){ union{float f; u32 i;} v; v.f=f; u32 u=v.i;
                     return (u16)((u + 0x7fffu + ((u>>16)&1u))>>16); }
// packed 2xf32 -> 2xbf16; lo = low 16 bits.  v_cvt_pk_bf16_f32 when available.
DI u32 pk2(float lo, float hi){
#if __has_builtin(__builtin_amdgcn_cvt_pk_bf16_f32)
  bf16x2t h = __builtin_amdgcn_cvt_pk_bf16_f32(lo, hi);
  u32 d; __builtin_memcpy(&d, &h, 4); return d;
#else
  return (u32)f2b(lo) | ((u32)f2b(hi)<<16);
#endif
}
// dtype-agnostic input load (element index): isbf ? bf16 : f32
DI float ldin(const void* p, size_t i, int isbf){
  return isbf ? b2f(((const u16*)p)[i]) : ((const float*)p)[i];
}
// 4 consecutive elements (i % 4 == 0)
DI f32x4 ldin4(const void* p, size_t i, int isbf){
  if(isbf){
    u32x2 d = *(const u32x2*)((const u16*)p + i);
    f32x4 r;
    r[0] = b2f((u16)(d[0]&0xffff)); r[1] = b2f((u16)(d[0]>>16));
    r[2] = b2f((u16)(d[1]&0xffff)); r[3] = b2f((u16)(d[1]>>16));
    return r;
  }
  return *(const f32x4*)((const float*)p + i);
}
DI int probe_bf(const void* nmask){ return ((const u16*)nmask)[0] == 0x3F80u; }

DI f32x4 mfma16(bf16x8 a, bf16x8 b, f32x4 c){
  return __builtin_amdgcn_mfma_f32_16x16x32_bf16(a,b,c,0,0,0);
}
// fragment (8 consecutive k as bf16) from fp32 global memory
DI bf16x8 ldfragA_f32(const float* p){
  f32x4 a = ((const f32x4*)p)[0], b = ((const f32x4*)p)[1];
  union{ u32 d[4]; bf16x8 v; } u;
  u.d[0]=pk2(a[0],a[1]); u.d[1]=pk2(a[2],a[3]);
  u.d[2]=pk2(b[0],b[1]); u.d[3]=pk2(b[2],b[3]);
  return u.v;
}
DI float sspf(float x){            // ssp = log(1+e^x) - ln2  (|x| << 80 guaranteed)
  return __logf(1.f + __expf(x)) - 0.6931471805599453f;
}

// ---------------------------------------------------------------------------
// Fused setup: blocks [0,4096) embed | [4096,6144) dist | [6144,6246) wfrag
__global__ __launch_bounds__(256) void k_setup(const void* __restrict__ pos,
                                               const void* __restrict__ cell,
                                               const void* __restrict__ cello,
                                               const void* __restrict__ nmask,
                                               const void* __restrict__ emb,
                                               const void* __restrict__ fw1,
                                               const void* __restrict__ fb1,
                                               const void* __restrict__ fw2,
                                               const void* __restrict__ in2f,
                                               const void* __restrict__ f2o,
                                               const void* __restrict__ den,
                                               const int* __restrict__ z,
                                               const int* __restrict__ nbrs,
                                               float* __restrict__ X,
                                               float* __restrict__ R,
                                               float* __restrict__ CM,
                                               u16* __restrict__ WF){
  int isbf = probe_bf(nmask);
  int bx = blockIdx.x, tid = threadIdx.x;
  if(bx < 4096){
    int idx = bx*256 + tid;                    // < 8192*128
    int a = idx>>7, f = idx&127;
    X[idx] = ldin(emb, (size_t)z[a]*128 + f, isbf);
    return;
  }
  if(bx < 6144){
    int pairIdx = (bx-4096)*256 + tid;         // < 8192*64
    int atom = pairIdx>>6;
    int b = atom>>10;
    int nb = nbrs[pairIdx];
    int jrow = (b<<10) + nb;
    float pi0=ldin(pos,atom*3+0,isbf), pi1=ldin(pos,atom*3+1,isbf), pi2=ldin(pos,atom*3+2,isbf);
    float pj0=ldin(pos,jrow*3+0,isbf), pj1=ldin(pos,jrow*3+1,isbf), pj2=ldin(pos,jrow*3+2,isbf);
    float co0=ldin(cello,(size_t)pairIdx*3+0,isbf),
          co1=ldin(cello,(size_t)pairIdx*3+1,isbf),
          co2=ldin(cello,(size_t)pairIdx*3+2,isbf);
    size_t cb = (size_t)b*9;
    pj0 += co0*ldin(cell,cb+0,isbf) + co1*ldin(cell,cb+3,isbf) + co2*ldin(cell,cb+6,isbf);
    pj1 += co0*ldin(cell,cb+1,isbf) + co1*ldin(cell,cb+4,isbf) + co2*ldin(cell,cb+7,isbf);
    pj2 += co0*ldin(cell,cb+2,isbf) + co1*ldin(cell,cb+5,isbf) + co2*ldin(cell,cb+8,isbf);
    float d0 = pj0-pi0, d1 = pj1-pi1, d2 = pj2-pi2;
    float dd = d0*d0 + d1*d1 + d2*d2;
    float m  = ldin(nmask,pairIdx,isbf);
    float r  = sqrtf(m>0.f ? dd : 1.f) * m;
    R[pairIdx] = r;
    float c = 0.5f*(__cosf(r*3.14159265358979f/5.f)+1.f) * ((r<5.f)?1.f:0.f) * m;
    CM[pairIdx] = c;
    return;
  }
  // weight fragments: wid in [0,408) = 3 interactions x 136 frags
  int wid = (bx-6144)*4 + (tid>>6);
  int lane = tid & 63;
  int q = lane>>4, l15 = lane&15;
  int i = wid/136, r = wid%136;
  int mat, kk, t;
  if(r < 8){ mat=0; kk=0; t=r; }
  else { int r2 = r-8; mat = 1 + (r2>>5); kk = (r2>>3)&3; t = r2&7; }
  const void* src; size_t sbase; int K; int off;
  switch(mat){
    case 0:  src = fw1;  sbase=(size_t)i*3200;  K=25;  off=0;     break;
    case 1:  src = fw2;  sbase=(size_t)i*16384; K=128; off=4096;  break;
    case 2:  src = in2f; sbase=(size_t)i*16384; K=128; off=20480; break;
    case 3:  src = f2o;  sbase=(size_t)i*16384; K=128; off=36864; break;
    default: src = den;  sbase=(size_t)i*16384; K=128; off=53248; break;
  }
  int c = t*16 + l15;
  bf16x8 frag;
  #pragma unroll
  for(int j=0;j<8;j++){
    int k = kk*32 + q*8 + j;
    float v;
    if(k < K)                 v = ldin(src, sbase + (size_t)k*128 + c, isbf);
    else if(mat==0 && k==25)  v = ldin(fb1, (size_t)i*128 + c, isbf);   // bias row
    else                      v = 0.f;
    frag[j] = (short)f2b(v);
  }
  *(bf16x8*)(WF + (size_t)i*69632 + off + ((kk*8+t)*64 + lane)*8) = frag;
}

// ---------------------------------------------------------------------------
// y = x @ in2f (iteration 0).  Transposed compute -> float4 Y stores.
__global__ __launch_bounds__(256) void k_proj(const float* __restrict__ X,
                                              const u16* __restrict__ wf,
                                              float* __restrict__ Y){
  int wid = blockIdx.x*4 + (threadIdx.x>>6);   // tile id < 512
  int lane = threadIdx.x & 63;
  int q = lane>>4, l15 = lane&15;
  int row0 = wid*16;
  f32x4 acc[8];
  #pragma unroll
  for(int t=0;t<8;t++) acc[t] = (f32x4){0.f,0.f,0.f,0.f};
  #pragma unroll
  for(int kk=0;kk<4;kk++){
    bf16x8 xf = ldfragA_f32(X + (size_t)(row0+l15)*128 + kk*32 + q*8);
    #pragma unroll
    for(int t=0;t<8;t++){
      bf16x8 wv = *(const bf16x8*)(wf + ((kk*8+t)*64 + lane)*8);
      acc[t] = mfma16(wv, xf, acc[t]);        // transposed: D[col t*16+q*4+r][row l15]
    }
  }
  #pragma unroll
  for(int t=0;t<8;t++)
    *(f32x4*)(Y + (size_t)(row0+l15)*128 + t*16 + q*4) = acc[t];
}

// ---------------------------------------------------------------------------
// CFConv: one wave per atom.  S1 transposed (bias in k=25 row, cutoff folded
// into ssp), packed b64 H writes, b128 H reads, w1 frags in block LDS.
__global__ __launch_bounds__(256,5) void k_cfconv(const float* __restrict__ R,
                                                  const float* __restrict__ CM,
                                                  const float* __restrict__ Y,
                                                  const int* __restrict__ nbrs,
                                                  const u16* __restrict__ fw1f,
                                                  const u16* __restrict__ fw2f,
                                                  const void* __restrict__ fb2,
                                                  const void* __restrict__ nmask,
                                                  float* __restrict__ AGG,
                                                  int iidx){
  __shared__ __align__(16) u16 W1s[4096];          // 8 KB: fw1 frags (block-shared)
  __shared__ __align__(16) u16 Hb[4][16][136];     // 17 KB: per-wave H tiles
  int isbf = probe_bf(nmask);
  int tid = threadIdx.x;
  int widx = tid>>6;
  int lane = tid & 63;
  int q = lane>>4, l15 = lane&15;
  int atom = blockIdx.x*4 + widx;
  int bbase = atom & ~1023;
  u16 (*H)[136] = Hb[widx];

  { // stage fw1 frags: 8192 B cooperative copy
    const u32x4* s4 = (const u32x4*)fw1f;
    u32x4* d4 = (u32x4*)W1s;
    d4[tid] = s4[tid];
    d4[tid+256] = s4[tid+256];
  }
  __syncthreads();

  float fb2v[8];
  #pragma unroll
  for(int t=0;t<8;t++) fb2v[t] = ldin(fb2,(size_t)iidx*128 + t*16+l15,isbf);
  float aggp[8];
  #pragma unroll
  for(int t=0;t<8;t++) aggp[t]=0.f;

  const float width = 5.0f/24.0f;
  const float coeff = -0.5f/(width*width);

  for(int mt=0; mt<4; mt++){
    asm volatile("s_waitcnt lgkmcnt(0)" ::: "memory");   // prev-mt H reads done
    float r    = R [(size_t)atom*64 + mt*16 + l15];
    float cm_l = CM[(size_t)atom*64 + mt*16 + l15];
    float ln2cm  = 0.69314718f*cm_l;
    // gaussian B-frag (k=25 -> 1.0 bias slot)
    float gv[8];
    #pragma unroll
    for(int j=0;j<8;j++){
      int k = q*8+j;
      if(k < 25){ float t = fmaf(-width,(float)k,r); gv[j] = __expf(coeff*t*t); }
      else gv[j] = (k==25) ? 1.f : 0.f;
    }
    union{ u32 d[4]; bf16x8 v; } afu;
    afu.d[0]=pk2(gv[0],gv[1]); afu.d[1]=pk2(gv[2],gv[3]);
    afu.d[2]=pk2(gv[4],gv[5]); afu.d[3]=pk2(gv[6],gv[7]);
    bf16x8 af = afu.v;

    // S1': Ht = fw1^T @ f^T  (lane holds H[nbr=l15][filt=t*16+q*4+r], bias incl.)
    f32x4 acc[8];
    #pragma unroll
    for(int t=0;t<8;t++){
      bf16x8 w1 = *(const bf16x8*)(W1s + t*512 + lane*8);
      acc[t] = mfma16(w1, af, (f32x4){0.f,0.f,0.f,0.f});
    }
    // h = cm * ssp(x);  pack pairs; one b64 write per t
    #pragma unroll
    for(int t=0;t<8;t++){
      float h0 = fmaf(__logf(1.f+__expf(acc[t][0])), cm_l, -ln2cm);
      float h1 = fmaf(__logf(1.f+__expf(acc[t][1])), cm_l, -ln2cm);
      float h2 = fmaf(__logf(1.f+__expf(acc[t][2])), cm_l, -ln2cm);
      float h3 = fmaf(__logf(1.f+__expf(acc[t][3])), cm_l, -ln2cm);
      u32x2 d; d[0]=pk2(h0,h1); d[1]=pk2(h2,h3);
      *(u32x2*)(&H[l15][t*16 + q*4]) = d;
    }
    asm volatile("s_waitcnt lgkmcnt(0)" ::: "memory");   // writes visible

    // S2: (C·H) @ fw2
    #pragma unroll
    for(int t=0;t<8;t++) acc[t] = (f32x4){0.f,0.f,0.f,0.f};
    #pragma unroll
    for(int kk=0;kk<4;kk++){
      bf16x8 a2 = *(const bf16x8*)(&H[l15][kk*32 + q*8]);
      #pragma unroll
      for(int t=0;t<8;t++){
        bf16x8 wv = *(const bf16x8*)(fw2f + ((kk*8+t)*64 + lane)*8);
        acc[t] = mfma16(a2, wv, acc[t]);
      }
    }
    // epilogue: agg += (acc + fb2*cm) * y[nbr]
    f32x4 cmv = *(const f32x4*)(CM + (size_t)atom*64 + mt*16 + q*4);
    int4  nb4 = *(const int4*)(nbrs + (size_t)atom*64 + mt*16 + q*4);
    #pragma unroll
    for(int t=0;t<8;t++){
      int col = t*16 + l15;
      float w0 = fmaf(fb2v[t], cmv[0], acc[t][0]);
      float w1 = fmaf(fb2v[t], cmv[1], acc[t][1]);
      float w2 = fmaf(fb2v[t], cmv[2], acc[t][2]);
      float w3 = fmaf(fb2v[t], cmv[3], acc[t][3]);
      aggp[t] = fmaf(w0, Y[(size_t)(bbase+nb4.x)*128+col], aggp[t]);
      aggp[t] = fmaf(w1, Y[(size_t)(bbase+nb4.y)*128+col], aggp[t]);
      aggp[t] = fmaf(w2, Y[(size_t)(bbase+nb4.z)*128+col], aggp[t]);
      aggp[t] = fmaf(w3, Y[(size_t)(bbase+nb4.w)*128+col], aggp[t]);
    }
  }
  #pragma unroll
  for(int t=0;t<8;t++){
    float v = aggp[t];
    v += __shfl_xor(v, 16, 64);
    v += __shfl_xor(v, 32, 64);
    aggp[t] = v;
  }
  if(q==0){
    #pragma unroll
    for(int t=0;t<8;t++) AGG[(size_t)atom*128 + t*16 + l15] = aggp[t];
  }
}

// ---------------------------------------------------------------------------
// v = ssp(agg @ f2out + b) @ dense + b;  x += v;  (if !last) y = x @ in2f_next
// All three GEMMs transposed -> b64 LDS writes, b128 reads, float4 X/Y stores.
__global__ __launch_bounds__(256) void k_out(const float* __restrict__ AGG,
                                             float* __restrict__ X,
                                             float* __restrict__ Y,
                                             const u16* __restrict__ f2of,
                                             const u16* __restrict__ denf,
                                             const u16* __restrict__ in2fN,
                                             const void* __restrict__ f2ob,
                                             const void* __restrict__ denb,
                                             const void* __restrict__ nmask,
                                             void* __restrict__ OUT,
                                             int last, int iidx){
  __shared__ __align__(16) u16 Tb[4][16][136];
  __shared__ __align__(16) u16 Xb[4][16][136];
  int isbf = probe_bf(nmask);
  int widx = threadIdx.x>>6;
  int lane = threadIdx.x & 63;
  int q = lane>>4, l15 = lane&15;
  int row0 = (blockIdx.x*4 + widx)*16;
  u16 (*T)[136]  = Tb[widx];
  u16 (*Xw)[136] = Xb[widx];

  // G1': T^T = f2o^T @ agg^T, then ssp(+bias)
  f32x4 acc[8];
  #pragma unroll
  for(int t=0;t<8;t++) acc[t] = (f32x4){0.f,0.f,0.f,0.f};
  #pragma unroll
  for(int kk=0;kk<4;kk++){
    bf16x8 gf = ldfragA_f32(AGG + (size_t)(row0+l15)*128 + kk*32 + q*8);
    #pragma unroll
    for(int t=0;t<8;t++){
      bf16x8 wv = *(const bf16x8*)(f2of + ((kk*8+t)*64 + lane)*8);
      acc[t] = mfma16(wv, gf, acc[t]);       // D[col t*16+q*4+r][row l15]
    }
  }
  #pragma unroll
  for(int t=0;t<8;t++){
    f32x4 bv = ldin4(f2ob, (size_t)iidx*128 + t*16 + q*4, isbf);
    u32x2 d;
    d[0] = pk2(sspf(acc[t][0]+bv[0]), sspf(acc[t][1]+bv[1]));
    d[1] = pk2(sspf(acc[t][2]+bv[2]), sspf(acc[t][3]+bv[3]));
    *(u32x2*)(&T[l15][t*16 + q*4]) = d;
  }
  asm volatile("s_waitcnt lgkmcnt(0)" ::: "memory");

  // G2': dense^T @ T^T + bias + X (residual)
  #pragma unroll
  for(int t=0;t<8;t++) acc[t] = (f32x4){0.f,0.f,0.f,0.f};
  #pragma unroll
  for(int kk=0;kk<4;kk++){
    bf16x8 tf = *(const bf16x8*)(&T[l15][kk*32 + q*8]);
    #pragma unroll
    for(int t=0;t<8;t++){
      bf16x8 wv = *(const bf16x8*)(denf + ((kk*8+t)*64 + lane)*8);
      acc[t] = mfma16(wv, tf, acc[t]);
    }
  }
  #pragma unroll
  for(int t=0;t<8;t++){
    size_t idx = (size_t)(row0+l15)*128 + t*16 + q*4;
    f32x4 bv = ldin4(denb, (size_t)iidx*128 + t*16 + q*4, isbf);
    f32x4 xv = *(const f32x4*)(X + idx);
    f32x4 xn;
    #pragma unroll
    for(int r=0;r<4;r++) xn[r] = xv[r] + acc[t][r] + bv[r];
    *(f32x4*)(X + idx) = xn;
    if(last){
      if(isbf){
        u32x2 o; o[0]=pk2(xn[0],xn[1]); o[1]=pk2(xn[2],xn[3]);
        *(u32x2*)((u16*)OUT + idx) = o;
      } else {
        *(f32x4*)((float*)OUT + idx) = xn;
      }
    } else {
      u32x2 d; d[0]=pk2(xn[0],xn[1]); d[1]=pk2(xn[2],xn[3]);
      *(u32x2*)(&Xw[l15][t*16 + q*4]) = d;
    }
  }
  if(!last){
    asm volatile("s_waitcnt lgkmcnt(0)" ::: "memory");
    // G3': y^T = in2f^T @ xnew^T  -> float4 Y stores
    #pragma unroll
    for(int t=0;t<8;t++) acc[t] = (f32x4){0.f,0.f,0.f,0.f};
    #pragma unroll
    for(int kk=0;kk<4;kk++){
      bf16x8 xf = *(const bf16x8*)(&Xw[l15][kk*32 + q*8]);
      #pragma unroll
      for(int t=0;t<8;t++){
        bf16x8 wv = *(const bf16x8*)(in2fN + ((kk*8+t)*64 + lane)*8);
        acc[t] = mfma16(wv, xf, acc[t]);
      }
    }
    #pragma unroll
    for(int t=0;t<8;t++)
      *(f32x4*)(Y + (size_t)(row0+l15)*128 + t*16 + q*4) = acc[t];
  }
}

// ---------------------------------------------------------------------------
extern "C" void kernel_launch(void* const* d_in, const int* in_sizes, int n_in,
                              void* d_out, int out_size, void* d_ws, size_t ws_size,
                              hipStream_t stream){
  const void* pos   = d_in[0];
  const void* cell  = d_in[1];
  const void* cello = d_in[2];
  const void* nmask = d_in[3];
  // d_in[4] atom_mask: unused by the output
  const void* emb   = d_in[5];
  const void* fw1   = d_in[6];
  const void* fb1   = d_in[7];
  const void* fw2   = d_in[8];
  const void* fb2   = d_in[9];
  const void* in2f  = d_in[10];
  const void* f2o   = d_in[11];
  const void* f2ob  = d_in[12];
  const void* den   = d_in[13];
  const void* denb  = d_in[14];
  const int* z      = (const int*)d_in[15];
  const int* nbrs   = (const int*)d_in[16];

  char* ws = (char*)d_ws;
  float* X   = (float*)(ws);                 //  4 MB fp32 features
  float* Y   = (float*)(ws +  4194304);      //  4 MB projected features
  float* AGG = (float*)(ws +  8388608);      //  4 MB cfconv aggregate
  float* R   = (float*)(ws + 12582912);      //  2 MB distances
  float* CMp = (float*)(ws + 14680064);      //  2 MB cutoff*mask
  u16*   WF  = (u16*)  (ws + 16777216);      // 408 KB weight B-frags

  k_setup<<<6246, 256, 0, stream>>>(pos, cell, cello, nmask, emb,
                                    fw1, fb1, fw2, in2f, f2o, den,
                                    z, nbrs, X, R, CMp, WF);
  k_proj <<< 128, 256, 0, stream>>>(X, WF + 20480, Y);

  for(int i=0;i<3;i++){
    const u16* base = WF + (size_t)i*69632;
    k_cfconv<<<2048, 256, 0, stream>>>(R, CMp, Y, nbrs,
                                       base + 0      /* fw1 frags (k=25 bias) */,
                                       base + 4096   /* fw2 frags */,
                                       fb2, nmask, AGG, i);
    const u16* in2fN = (i<2) ? (WF + (size_t)(i+1)*69632 + 20480) : WF;
    k_out<<<128, 256, 0, stream>>>(AGG, X, Y,
                                   base + 36864 /* f2out frags */,
                                   base + 53248 /* dense frags */,
                                   in2fN,
                                   f2ob, denb, nmask,
                                   d_out, (i==2) ? 1 : 0, i);
  }
}

// Round 5
// 625.387 us; speedup vs baseline: 1.2132x; 1.2132x over previous
//
#include <hip/hip_runtime.h>

typedef __attribute__((ext_vector_type(8))) short bf16x8;
typedef __attribute__((ext_vector_type(4))) float f32x4;
typedef __attribute__((ext_vector_type(2))) unsigned int u32x2;
typedef __attribute__((ext_vector_type(4))) unsigned int u32x4;
typedef __attribute__((ext_vector_type(2))) __bf16 bf16x2t;
typedef unsigned short u16;
typedef unsigned int u32;

#define DI __device__ __forceinline__

// Problem constants: B=8, A=1024, NB=64, NAB=NF=128, NG=25, NI=3

DI float b2f(u16 u){ union{u32 i; float f;} v; v.i = ((u32)u)<<16; return v.f; }
DI u16 f2b(float f){ union{float f; u32 i;} v; v.f=f; u32 u=v.i;
                     return (u16)((u + 0x7fffu + ((u>>16)&1u))>>16); }
// packed 2xf32 -> 2xbf16; lo = low 16 bits.  v_cvt_pk_bf16_f32 when available.
DI u32 pk2(float lo, float hi){
#if __has_builtin(__builtin_amdgcn_cvt_pk_bf16_f32)
  bf16x2t h = __builtin_amdgcn_cvt_pk_bf16_f32(lo, hi);
  u32 d; __builtin_memcpy(&d, &h, 4); return d;
#else
  return (u32)f2b(lo) | ((u32)f2b(hi)<<16);
#endif
}
// dtype-agnostic input load (element index): isbf ? bf16 : f32
DI float ldin(const void* p, size_t i, int isbf){
  return isbf ? b2f(((const u16*)p)[i]) : ((const float*)p)[i];
}
// 4 consecutive elements (i % 4 == 0)
DI f32x4 ldin4(const void* p, size_t i, int isbf){
  if(isbf){
    u32x2 d = *(const u32x2*)((const u16*)p + i);
    f32x4 r;
    r[0] = b2f((u16)(d[0]&0xffff)); r[1] = b2f((u16)(d[0]>>16));
    r[2] = b2f((u16)(d[1]&0xffff)); r[3] = b2f((u16)(d[1]>>16));
    return r;
  }
  return *(const f32x4*)((const float*)p + i);
}
DI int probe_bf(const void* nmask){ return ((const u16*)nmask)[0] == 0x3F80u; }

DI f32x4 mfma16(bf16x8 a, bf16x8 b, f32x4 c){
  return __builtin_amdgcn_mfma_f32_16x16x32_bf16(a,b,c,0,0,0);
}
// fragment (8 consecutive k as bf16) from fp32 global memory
DI bf16x8 ldfragA_f32(const float* p){
  f32x4 a = ((const f32x4*)p)[0], b = ((const f32x4*)p)[1];
  union{ u32 d[4]; bf16x8 v; } u;
  u.d[0]=pk2(a[0],a[1]); u.d[1]=pk2(a[2],a[3]);
  u.d[2]=pk2(b[0],b[1]); u.d[3]=pk2(b[2],b[3]);
  return u.v;
}
DI float sspf(float x){            // ssp = log(1+e^x) - ln2  (|x| << 80 guaranteed)
  return __logf(1.f + __expf(x)) - 0.6931471805599453f;
}

// ---------------------------------------------------------------------------
// Fused setup: blocks [0,4096) embed | [4096,6144) dist | [6144,6246) wfrag
__global__ __launch_bounds__(256) void k_setup(const void* __restrict__ pos,
                                               const void* __restrict__ cell,
                                               const void* __restrict__ cello,
                                               const void* __restrict__ nmask,
                                               const void* __restrict__ emb,
                                               const void* __restrict__ fw1,
                                               const void* __restrict__ fb1,
                                               const void* __restrict__ fw2,
                                               const void* __restrict__ in2f,
                                               const void* __restrict__ f2o,
                                               const void* __restrict__ den,
                                               const int* __restrict__ z,
                                               const int* __restrict__ nbrs,
                                               float* __restrict__ X,
                                               float* __restrict__ R,
                                               float* __restrict__ CM,
                                               u16* __restrict__ WF){
  int isbf = probe_bf(nmask);
  int bx = blockIdx.x, tid = threadIdx.x;
  if(bx < 4096){
    int idx = bx*256 + tid;                    // < 8192*128
    int a = idx>>7, f = idx&127;
    X[idx] = ldin(emb, (size_t)z[a]*128 + f, isbf);
    return;
  }
  if(bx < 6144){
    int pairIdx = (bx-4096)*256 + tid;         // < 8192*64
    int atom = pairIdx>>6;
    int b = atom>>10;
    int nb = nbrs[pairIdx];
    int jrow = (b<<10) + nb;
    float pi0=ldin(pos,atom*3+0,isbf), pi1=ldin(pos,atom*3+1,isbf), pi2=ldin(pos,atom*3+2,isbf);
    float pj0=ldin(pos,jrow*3+0,isbf), pj1=ldin(pos,jrow*3+1,isbf), pj2=ldin(pos,jrow*3+2,isbf);
    float co0=ldin(cello,(size_t)pairIdx*3+0,isbf),
          co1=ldin(cello,(size_t)pairIdx*3+1,isbf),
          co2=ldin(cello,(size_t)pairIdx*3+2,isbf);
    size_t cb = (size_t)b*9;
    pj0 += co0*ldin(cell,cb+0,isbf) + co1*ldin(cell,cb+3,isbf) + co2*ldin(cell,cb+6,isbf);
    pj1 += co0*ldin(cell,cb+1,isbf) + co1*ldin(cell,cb+4,isbf) + co2*ldin(cell,cb+7,isbf);
    pj2 += co0*ldin(cell,cb+2,isbf) + co1*ldin(cell,cb+5,isbf) + co2*ldin(cell,cb+8,isbf);
    float d0 = pj0-pi0, d1 = pj1-pi1, d2 = pj2-pi2;
    float dd = d0*d0 + d1*d1 + d2*d2;
    float m  = ldin(nmask,pairIdx,isbf);
    float r  = sqrtf(m>0.f ? dd : 1.f) * m;
    R[pairIdx] = r;
    float c = 0.5f*(__cosf(r*3.14159265358979f/5.f)+1.f) * ((r<5.f)?1.f:0.f) * m;
    CM[pairIdx] = c;
    return;
  }
  // weight fragments: wid in [0,408) = 3 interactions x 136 frags
  int wid = (bx-6144)*4 + (tid>>6);
  int lane = tid & 63;
  int q = lane>>4, l15 = lane&15;
  int i = wid/136, r = wid%136;
  int mat, kk, t;
  if(r < 8){ mat=0; kk=0; t=r; }
  else { int r2 = r-8; mat = 1 + (r2>>5); kk = (r2>>3)&3; t = r2&7; }
  const void* src; size_t sbase; int K; int off;
  switch(mat){
    case 0:  src = fw1;  sbase=(size_t)i*3200;  K=25;  off=0;     break;
    case 1:  src = fw2;  sbase=(size_t)i*16384; K=128; off=4096;  break;
    case 2:  src = in2f; sbase=(size_t)i*16384; K=128; off=20480; break;
    case 3:  src = f2o;  sbase=(size_t)i*16384; K=128; off=36864; break;
    default: src = den;  sbase=(size_t)i*16384; K=128; off=53248; break;
  }
  int c = t*16 + l15;
  bf16x8 frag;
  #pragma unroll
  for(int j=0;j<8;j++){
    int k = kk*32 + q*8 + j;
    float v;
    if(k < K)                 v = ldin(src, sbase + (size_t)k*128 + c, isbf);
    else if(mat==0 && k==25)  v = ldin(fb1, (size_t)i*128 + c, isbf);   // bias row
    else                      v = 0.f;
    frag[j] = (short)f2b(v);
  }
  *(bf16x8*)(WF + (size_t)i*69632 + off + ((kk*8+t)*64 + lane)*8) = frag;
}

// ---------------------------------------------------------------------------
// y = x @ in2f (iteration 0).  Transposed compute -> float4 Y stores.
__global__ __launch_bounds__(256) void k_proj(const float* __restrict__ X,
                                              const u16* __restrict__ wf,
                                              float* __restrict__ Y){
  int wid = blockIdx.x*4 + (threadIdx.x>>6);   // tile id < 512
  int lane = threadIdx.x & 63;
  int q = lane>>4, l15 = lane&15;
  int row0 = wid*16;
  f32x4 acc[8];
  #pragma unroll
  for(int t=0;t<8;t++) acc[t] = (f32x4){0.f,0.f,0.f,0.f};
  #pragma unroll
  for(int kk=0;kk<4;kk++){
    bf16x8 xf = ldfragA_f32(X + (size_t)(row0+l15)*128 + kk*32 + q*8);
    #pragma unroll
    for(int t=0;t<8;t++){
      bf16x8 wv = *(const bf16x8*)(wf + ((kk*8+t)*64 + lane)*8);
      acc[t] = mfma16(wv, xf, acc[t]);        // transposed: D[col t*16+q*4+r][row l15]
    }
  }
  #pragma unroll
  for(int t=0;t<8;t++)
    *(f32x4*)(Y + (size_t)(row0+l15)*128 + t*16 + q*4) = acc[t];
}

// ---------------------------------------------------------------------------
// CFConv: one wave per atom.  S1 transposed (bias in k=25 row, cutoff folded
// into ssp), packed b64 H writes, b128 H reads, w1 frags in block LDS.
// __launch_bounds__(256,4): R4's (256,5) forced VGPR=48 -> catastrophic
// scratch spills (WRITE_SIZE 4->141 MB). 4 waves/EU fits without spilling.
__global__ __launch_bounds__(256,4) void k_cfconv(const float* __restrict__ R,
                                                  const float* __restrict__ CM,
                                                  const float* __restrict__ Y,
                                                  const int* __restrict__ nbrs,
                                                  const u16* __restrict__ fw1f,
                                                  const u16* __restrict__ fw2f,
                                                  const void* __restrict__ fb2,
                                                  const void* __restrict__ nmask,
                                                  float* __restrict__ AGG,
                                                  int iidx){
  __shared__ __align__(16) u16 W1s[4096];          // 8 KB: fw1 frags (block-shared)
  __shared__ __align__(16) u16 Hb[4][16][136];     // 17 KB: per-wave H tiles
  int isbf = probe_bf(nmask);
  int tid = threadIdx.x;
  int widx = tid>>6;
  int lane = tid & 63;
  int q = lane>>4, l15 = lane&15;
  int atom = blockIdx.x*4 + widx;
  int bbase = atom & ~1023;
  u16 (*H)[136] = Hb[widx];

  { // stage fw1 frags: 8192 B cooperative copy
    const u32x4* s4 = (const u32x4*)fw1f;
    u32x4* d4 = (u32x4*)W1s;
    d4[tid] = s4[tid];
    d4[tid+256] = s4[tid+256];
  }
  __syncthreads();

  float fb2v[8];
  #pragma unroll
  for(int t=0;t<8;t++) fb2v[t] = ldin(fb2,(size_t)iidx*128 + t*16+l15,isbf);
  float aggp[8];
  #pragma unroll
  for(int t=0;t<8;t++) aggp[t]=0.f;

  const float width = 5.0f/24.0f;
  const float coeff = -0.5f/(width*width);

  for(int mt=0; mt<4; mt++){
    asm volatile("s_waitcnt lgkmcnt(0)" ::: "memory");   // prev-mt H reads done
    float r    = R [(size_t)atom*64 + mt*16 + l15];
    float cm_l = CM[(size_t)atom*64 + mt*16 + l15];
    float ln2cm  = 0.69314718f*cm_l;
    // gaussian B-frag (k=25 -> 1.0 bias slot)
    float gv[8];
    #pragma unroll
    for(int j=0;j<8;j++){
      int k = q*8+j;
      if(k < 25){ float t = fmaf(-width,(float)k,r); gv[j] = __expf(coeff*t*t); }
      else gv[j] = (k==25) ? 1.f : 0.f;
    }
    union{ u32 d[4]; bf16x8 v; } afu;
    afu.d[0]=pk2(gv[0],gv[1]); afu.d[1]=pk2(gv[2],gv[3]);
    afu.d[2]=pk2(gv[4],gv[5]); afu.d[3]=pk2(gv[6],gv[7]);
    bf16x8 af = afu.v;

    // S1': Ht = fw1^T @ f^T  (lane holds H[nbr=l15][filt=t*16+q*4+r], bias incl.)
    f32x4 acc[8];
    #pragma unroll
    for(int t=0;t<8;t++){
      bf16x8 w1 = *(const bf16x8*)(W1s + t*512 + lane*8);
      acc[t] = mfma16(w1, af, (f32x4){0.f,0.f,0.f,0.f});
    }
    // h = cm * ssp(x);  pack pairs; one b64 write per t
    #pragma unroll
    for(int t=0;t<8;t++){
      float h0 = fmaf(__logf(1.f+__expf(acc[t][0])), cm_l, -ln2cm);
      float h1 = fmaf(__logf(1.f+__expf(acc[t][1])), cm_l, -ln2cm);
      float h2 = fmaf(__logf(1.f+__expf(acc[t][2])), cm_l, -ln2cm);
      float h3 = fmaf(__logf(1.f+__expf(acc[t][3])), cm_l, -ln2cm);
      u32x2 d; d[0]=pk2(h0,h1); d[1]=pk2(h2,h3);
      *(u32x2*)(&H[l15][t*16 + q*4]) = d;
    }
    asm volatile("s_waitcnt lgkmcnt(0)" ::: "memory");   // writes visible

    // S2: (C·H) @ fw2
    #pragma unroll
    for(int t=0;t<8;t++) acc[t] = (f32x4){0.f,0.f,0.f,0.f};
    #pragma unroll
    for(int kk=0;kk<4;kk++){
      bf16x8 a2 = *(const bf16x8*)(&H[l15][kk*32 + q*8]);
      #pragma unroll
      for(int t=0;t<8;t++){
        bf16x8 wv = *(const bf16x8*)(fw2f + ((kk*8+t)*64 + lane)*8);
        acc[t] = mfma16(a2, wv, acc[t]);
      }
    }
    // epilogue: agg += (acc + fb2*cm) * y[nbr]
    f32x4 cmv = *(const f32x4*)(CM + (size_t)atom*64 + mt*16 + q*4);
    int4  nb4 = *(const int4*)(nbrs + (size_t)atom*64 + mt*16 + q*4);
    #pragma unroll
    for(int t=0;t<8;t++){
      int col = t*16 + l15;
      float w0 = fmaf(fb2v[t], cmv[0], acc[t][0]);
      float w1 = fmaf(fb2v[t], cmv[1], acc[t][1]);
      float w2 = fmaf(fb2v[t], cmv[2], acc[t][2]);
      float w3 = fmaf(fb2v[t], cmv[3], acc[t][3]);
      aggp[t] = fmaf(w0, Y[(size_t)(bbase+nb4.x)*128+col], aggp[t]);
      aggp[t] = fmaf(w1, Y[(size_t)(bbase+nb4.y)*128+col], aggp[t]);
      aggp[t] = fmaf(w2, Y[(size_t)(bbase+nb4.z)*128+col], aggp[t]);
      aggp[t] = fmaf(w3, Y[(size_t)(bbase+nb4.w)*128+col], aggp[t]);
    }
  }
  #pragma unroll
  for(int t=0;t<8;t++){
    float v = aggp[t];
    v += __shfl_xor(v, 16, 64);
    v += __shfl_xor(v, 32, 64);
    aggp[t] = v;
  }
  if(q==0){
    #pragma unroll
    for(int t=0;t<8;t++) AGG[(size_t)atom*128 + t*16 + l15] = aggp[t];
  }
}

// ---------------------------------------------------------------------------
// v = ssp(agg @ f2out + b) @ dense + b;  x += v;  (if !last) y = x @ in2f_next
// All three GEMMs transposed -> b64 LDS writes, b128 reads, float4 X/Y stores.
__global__ __launch_bounds__(256) void k_out(const float* __restrict__ AGG,
                                             float* __restrict__ X,
                                             float* __restrict__ Y,
                                             const u16* __restrict__ f2of,
                                             const u16* __restrict__ denf,
                                             const u16* __restrict__ in2fN,
                                             const void* __restrict__ f2ob,
                                             const void* __restrict__ denb,
                                             const void* __restrict__ nmask,
                                             void* __restrict__ OUT,
                                             int last, int iidx){
  __shared__ __align__(16) u16 Tb[4][16][136];
  __shared__ __align__(16) u16 Xb[4][16][136];
  int isbf = probe_bf(nmask);
  int widx = threadIdx.x>>6;
  int lane = threadIdx.x & 63;
  int q = lane>>4, l15 = lane&15;
  int row0 = (blockIdx.x*4 + widx)*16;
  u16 (*T)[136]  = Tb[widx];
  u16 (*Xw)[136] = Xb[widx];

  // G1': T^T = f2o^T @ agg^T, then ssp(+bias)
  f32x4 acc[8];
  #pragma unroll
  for(int t=0;t<8;t++) acc[t] = (f32x4){0.f,0.f,0.f,0.f};
  #pragma unroll
  for(int kk=0;kk<4;kk++){
    bf16x8 gf = ldfragA_f32(AGG + (size_t)(row0+l15)*128 + kk*32 + q*8);
    #pragma unroll
    for(int t=0;t<8;t++){
      bf16x8 wv = *(const bf16x8*)(f2of + ((kk*8+t)*64 + lane)*8);
      acc[t] = mfma16(wv, gf, acc[t]);       // D[col t*16+q*4+r][row l15]
    }
  }
  #pragma unroll
  for(int t=0;t<8;t++){
    f32x4 bv = ldin4(f2ob, (size_t)iidx*128 + t*16 + q*4, isbf);
    u32x2 d;
    d[0] = pk2(sspf(acc[t][0]+bv[0]), sspf(acc[t][1]+bv[1]));
    d[1] = pk2(sspf(acc[t][2]+bv[2]), sspf(acc[t][3]+bv[3]));
    *(u32x2*)(&T[l15][t*16 + q*4]) = d;
  }
  asm volatile("s_waitcnt lgkmcnt(0)" ::: "memory");

  // G2': dense^T @ T^T + bias + X (residual)
  #pragma unroll
  for(int t=0;t<8;t++) acc[t] = (f32x4){0.f,0.f,0.f,0.f};
  #pragma unroll
  for(int kk=0;kk<4;kk++){
    bf16x8 tf = *(const bf16x8*)(&T[l15][kk*32 + q*8]);
    #pragma unroll
    for(int t=0;t<8;t++){
      bf16x8 wv = *(const bf16x8*)(denf + ((kk*8+t)*64 + lane)*8);
      acc[t] = mfma16(wv, tf, acc[t]);
    }
  }
  #pragma unroll
  for(int t=0;t<8;t++){
    size_t idx = (size_t)(row0+l15)*128 + t*16 + q*4;
    f32x4 bv = ldin4(denb, (size_t)iidx*128 + t*16 + q*4, isbf);
    f32x4 xv = *(const f32x4*)(X + idx);
    f32x4 xn;
    #pragma unroll
    for(int r=0;r<4;r++) xn[r] = xv[r] + acc[t][r] + bv[r];
    *(f32x4*)(X + idx) = xn;
    if(last){
      if(isbf){
        u32x2 o; o[0]=pk2(xn[0],xn[1]); o[1]=pk2(xn[2],xn[3]);
        *(u32x2*)((u16*)OUT + idx) = o;
      } else {
        *(f32x4*)((float*)OUT + idx) = xn;
      }
    } else {
      u32x2 d; d[0]=pk2(xn[0],xn[1]); d[1]=pk2(xn[2],xn[3]);
      *(u32x2*)(&Xw[l15][t*16 + q*4]) = d;
    }
  }
  if(!last){
    asm volatile("s_waitcnt lgkmcnt(0)" ::: "memory");
    // G3': y^T = in2f^T @ xnew^T  -> float4 Y stores
    #pragma unroll
    for(int t=0;t<8;t++) acc[t] = (f32x4){0.f,0.f,0.f,0.f};
    #pragma unroll
    for(int kk=0;kk<4;kk++){
      bf16x8 xf = *(const bf16x8*)(&Xw[l15][kk*32 + q*8]);
      #pragma unroll
      for(int t=0;t<8;t++){
        bf16x8 wv = *(const bf16x8*)(in2fN + ((kk*8+t)*64 + lane)*8);
        acc[t] = mfma16(wv, xf, acc[t]);
      }
    }
    #pragma unroll
    for(int t=0;t<8;t++)
      *(f32x4*)(Y + (size_t)(row0+l15)*128 + t*16 + q*4) = acc[t];
  }
}

// ---------------------------------------------------------------------------
extern "C" void kernel_launch(void* const* d_in, const int* in_sizes, int n_in,
                              void* d_out, int out_size, void* d_ws, size_t ws_size,
                              hipStream_t stream){
  const void* pos   = d_in[0];
  const void* cell  = d_in[1];
  const void* cello = d_in[2];
  const void* nmask = d_in[3];
  // d_in[4] atom_mask: unused by the output
  const void* emb   = d_in[5];
  const void* fw1   = d_in[6];
  const void* fb1   = d_in[7];
  const void* fw2   = d_in[8];
  const void* fb2   = d_in[9];
  const void* in2f  = d_in[10];
  const void* f2o   = d_in[11];
  const void* f2ob  = d_in[12];
  const void* den   = d_in[13];
  const void* denb  = d_in[14];
  const int* z      = (const int*)d_in[15];
  const int* nbrs   = (const int*)d_in[16];

  char* ws = (char*)d_ws;
  float* X   = (float*)(ws);                 //  4 MB fp32 features
  float* Y   = (float*)(ws +  4194304);      //  4 MB projected features
  float* AGG = (float*)(ws +  8388608);      //  4 MB cfconv aggregate
  float* R   = (float*)(ws + 12582912);      //  2 MB distances
  float* CMp = (float*)(ws + 14680064);      //  2 MB cutoff*mask
  u16*   WF  = (u16*)  (ws + 16777216);      // 408 KB weight B-frags

  k_setup<<<6246, 256, 0, stream>>>(pos, cell, cello, nmask, emb,
                                    fw1, fb1, fw2, in2f, f2o, den,
                                    z, nbrs, X, R, CMp, WF);
  k_proj <<< 128, 256, 0, stream>>>(X, WF + 20480, Y);

  for(int i=0;i<3;i++){
    const u16* base = WF + (size_t)i*69632;
    k_cfconv<<<2048, 256, 0, stream>>>(R, CMp, Y, nbrs,
                                       base + 0      /* fw1 frags (k=25 bias) */,
                                       base + 4096   /* fw2 frags */,
                                       fb2, nmask, AGG, i);
    const u16* in2fN = (i<2) ? (WF + (size_t)(i+1)*69632 + 20480) : WF;
    k_out<<<128, 256, 0, stream>>>(AGG, X, Y,
                                   base + 36864 /* f2out frags */,
                                   base + 53248 /* dense frags */,
                                   in2fN,
                                   f2ob, denb, nmask,
                                   d_out, (i==2) ? 1 : 0, i);
  }
}

// Round 6
// 375.439 us; speedup vs baseline: 2.0209x; 1.6657x over previous
//
#include <hip/hip_runtime.h>

typedef __attribute__((ext_vector_type(8))) short bf16x8;
typedef __attribute__((ext_vector_type(4))) float f32x4;
typedef __attribute__((ext_vector_type(2))) unsigned int u32x2;
typedef __attribute__((ext_vector_type(4))) unsigned int u32x4;
typedef __attribute__((ext_vector_type(2))) __bf16 bf16x2t;
typedef unsigned short u16;
typedef unsigned int u32;

#define DI __device__ __forceinline__

// Problem constants: B=8, A=1024, NB=64, NAB=NF=128, NG=25, NI=3

DI float b2f(u16 u){ union{u32 i; float f;} v; v.i = ((u32)u)<<16; return v.f; }
DI u16 f2b(float f){ union{float f; u32 i;} v; v.f=f; u32 u=v.i;
                     return (u16)((u + 0x7fffu + ((u>>16)&1u))>>16); }
// packed 2xf32 -> 2xbf16; lo = low 16 bits.  v_cvt_pk_bf16_f32 when available.
DI u32 pk2(float lo, float hi){
#if __has_builtin(__builtin_amdgcn_cvt_pk_bf16_f32)
  bf16x2t h = __builtin_amdgcn_cvt_pk_bf16_f32(lo, hi);
  u32 d; __builtin_memcpy(&d, &h, 4); return d;
#else
  return (u32)f2b(lo) | ((u32)f2b(hi)<<16);
#endif
}
// dtype-agnostic input load (element index): isbf ? bf16 : f32
DI float ldin(const void* p, size_t i, int isbf){
  return isbf ? b2f(((const u16*)p)[i]) : ((const float*)p)[i];
}
// 4 consecutive elements (i % 4 == 0)
DI f32x4 ldin4(const void* p, size_t i, int isbf){
  if(isbf){
    u32x2 d = *(const u32x2*)((const u16*)p + i);
    f32x4 r;
    r[0] = b2f((u16)(d[0]&0xffff)); r[1] = b2f((u16)(d[0]>>16));
    r[2] = b2f((u16)(d[1]&0xffff)); r[3] = b2f((u16)(d[1]>>16));
    return r;
  }
  return *(const f32x4*)((const float*)p + i);
}
DI int probe_bf(const void* nmask){ return ((const u16*)nmask)[0] == 0x3F80u; }

DI f32x4 mfma16(bf16x8 a, bf16x8 b, f32x4 c){
  return __builtin_amdgcn_mfma_f32_16x16x32_bf16(a,b,c,0,0,0);
}
// fragment (8 consecutive k as bf16) from fp32 global memory
DI bf16x8 ldfragA_f32(const float* p){
  f32x4 a = ((const f32x4*)p)[0], b = ((const f32x4*)p)[1];
  union{ u32 d[4]; bf16x8 v; } u;
  u.d[0]=pk2(a[0],a[1]); u.d[1]=pk2(a[2],a[3]);
  u.d[2]=pk2(b[0],b[1]); u.d[3]=pk2(b[2],b[3]);
  return u.v;
}
DI float sspf(float x){            // ssp = log(1+e^x) - ln2  (|x| << 80 guaranteed)
  return __logf(1.f + __expf(x)) - 0.6931471805599453f;
}

// ---------------------------------------------------------------------------
// Fused setup: blocks [0,4096) embed | [4096,6144) dist | [6144,6246) wfrag
__global__ __launch_bounds__(256) void k_setup(const void* __restrict__ pos,
                                               const void* __restrict__ cell,
                                               const void* __restrict__ cello,
                                               const void* __restrict__ nmask,
                                               const void* __restrict__ emb,
                                               const void* __restrict__ fw1,
                                               const void* __restrict__ fb1,
                                               const void* __restrict__ fw2,
                                               const void* __restrict__ in2f,
                                               const void* __restrict__ f2o,
                                               const void* __restrict__ den,
                                               const int* __restrict__ z,
                                               const int* __restrict__ nbrs,
                                               float* __restrict__ X,
                                               float* __restrict__ R,
                                               float* __restrict__ CM,
                                               u16* __restrict__ WF){
  int isbf = probe_bf(nmask);
  int bx = blockIdx.x, tid = threadIdx.x;
  if(bx < 4096){
    int idx = bx*256 + tid;                    // < 8192*128
    int a = idx>>7, f = idx&127;
    X[idx] = ldin(emb, (size_t)z[a]*128 + f, isbf);
    return;
  }
  if(bx < 6144){
    int pairIdx = (bx-4096)*256 + tid;         // < 8192*64
    int atom = pairIdx>>6;
    int b = atom>>10;
    int nb = nbrs[pairIdx];
    int jrow = (b<<10) + nb;
    float pi0=ldin(pos,atom*3+0,isbf), pi1=ldin(pos,atom*3+1,isbf), pi2=ldin(pos,atom*3+2,isbf);
    float pj0=ldin(pos,jrow*3+0,isbf), pj1=ldin(pos,jrow*3+1,isbf), pj2=ldin(pos,jrow*3+2,isbf);
    float co0=ldin(cello,(size_t)pairIdx*3+0,isbf),
          co1=ldin(cello,(size_t)pairIdx*3+1,isbf),
          co2=ldin(cello,(size_t)pairIdx*3+2,isbf);
    size_t cb = (size_t)b*9;
    pj0 += co0*ldin(cell,cb+0,isbf) + co1*ldin(cell,cb+3,isbf) + co2*ldin(cell,cb+6,isbf);
    pj1 += co0*ldin(cell,cb+1,isbf) + co1*ldin(cell,cb+4,isbf) + co2*ldin(cell,cb+7,isbf);
    pj2 += co0*ldin(cell,cb+2,isbf) + co1*ldin(cell,cb+5,isbf) + co2*ldin(cell,cb+8,isbf);
    float d0 = pj0-pi0, d1 = pj1-pi1, d2 = pj2-pi2;
    float dd = d0*d0 + d1*d1 + d2*d2;
    float m  = ldin(nmask,pairIdx,isbf);
    float r  = sqrtf(m>0.f ? dd : 1.f) * m;
    R[pairIdx] = r;
    float c = 0.5f*(__cosf(r*3.14159265358979f/5.f)+1.f) * ((r<5.f)?1.f:0.f) * m;
    CM[pairIdx] = c;
    return;
  }
  // weight fragments: wid in [0,408) = 3 interactions x 136 frags
  int wid = (bx-6144)*4 + (tid>>6);
  int lane = tid & 63;
  int q = lane>>4, l15 = lane&15;
  int i = wid/136, r = wid%136;
  int mat, kk, t;
  if(r < 8){ mat=0; kk=0; t=r; }
  else { int r2 = r-8; mat = 1 + (r2>>5); kk = (r2>>3)&3; t = r2&7; }
  const void* src; size_t sbase; int K; int off;
  switch(mat){
    case 0:  src = fw1;  sbase=(size_t)i*3200;  K=25;  off=0;     break;
    case 1:  src = fw2;  sbase=(size_t)i*16384; K=128; off=4096;  break;
    case 2:  src = in2f; sbase=(size_t)i*16384; K=128; off=20480; break;
    case 3:  src = f2o;  sbase=(size_t)i*16384; K=128; off=36864; break;
    default: src = den;  sbase=(size_t)i*16384; K=128; off=53248; break;
  }
  int c = t*16 + l15;
  bf16x8 frag;
  #pragma unroll
  for(int j=0;j<8;j++){
    int k = kk*32 + q*8 + j;
    float v;
    if(k < K)                 v = ldin(src, sbase + (size_t)k*128 + c, isbf);
    else if(mat==0 && k==25)  v = ldin(fb1, (size_t)i*128 + c, isbf);   // bias row
    else                      v = 0.f;
    frag[j] = (short)f2b(v);
  }
  *(bf16x8*)(WF + (size_t)i*69632 + off + ((kk*8+t)*64 + lane)*8) = frag;
}

// ---------------------------------------------------------------------------
// y = x @ in2f (iteration 0).  Transposed compute -> float4 Y stores.
__global__ __launch_bounds__(256) void k_proj(const float* __restrict__ X,
                                              const u16* __restrict__ wf,
                                              float* __restrict__ Y){
  int wid = blockIdx.x*4 + (threadIdx.x>>6);   // tile id < 512
  int lane = threadIdx.x & 63;
  int q = lane>>4, l15 = lane&15;
  int row0 = wid*16;
  f32x4 acc[8];
  #pragma unroll
  for(int t=0;t<8;t++) acc[t] = (f32x4){0.f,0.f,0.f,0.f};
  #pragma unroll
  for(int kk=0;kk<4;kk++){
    bf16x8 xf = ldfragA_f32(X + (size_t)(row0+l15)*128 + kk*32 + q*8);
    #pragma unroll
    for(int t=0;t<8;t++){
      bf16x8 wv = *(const bf16x8*)(wf + ((kk*8+t)*64 + lane)*8);
      acc[t] = mfma16(wv, xf, acc[t]);        // transposed: D[col t*16+q*4+r][row l15]
    }
  }
  #pragma unroll
  for(int t=0;t<8;t++)
    *(f32x4*)(Y + (size_t)(row0+l15)*128 + t*16 + q*4) = acc[t];
}

// ---------------------------------------------------------------------------
// CFConv: one wave per atom.  S1 transposed (bias in k=25 row, cutoff folded
// into ssp), packed b64 H writes, b128 H reads, w1 frags in block LDS.
// NOTE on launch bounds (R4/R5 lesson): gfx950 has a UNIFIED VGPR/AGPR file;
// __launch_bounds__(256,4) gives a 128-reg TOTAL budget which the compiler
// split 64 arch + 64 acc -> heavy scratch spills (WRITE_SIZE 4->65 MB).
// Plain (256) lets the allocator take ~120 arch VGPRs spill-free (R2: 4 MB
// WRITE, no spill).  Do NOT add a min-waves arg here.
__global__ __launch_bounds__(256) void k_cfconv(const float* __restrict__ R,
                                                const float* __restrict__ CM,
                                                const float* __restrict__ Y,
                                                const int* __restrict__ nbrs,
                                                const u16* __restrict__ fw1f,
                                                const u16* __restrict__ fw2f,
                                                const void* __restrict__ fb2,
                                                const void* __restrict__ nmask,
                                                float* __restrict__ AGG,
                                                int iidx){
  __shared__ __align__(16) u16 W1s[4096];          // 8 KB: fw1 frags (block-shared)
  __shared__ __align__(16) u16 Hb[4][16][136];     // 17 KB: per-wave H tiles
  int isbf = probe_bf(nmask);
  int tid = threadIdx.x;
  int widx = tid>>6;
  int lane = tid & 63;
  int q = lane>>4, l15 = lane&15;
  int atom = blockIdx.x*4 + widx;
  int bbase = atom & ~1023;
  u16 (*H)[136] = Hb[widx];

  { // stage fw1 frags: 8192 B cooperative copy
    const u32x4* s4 = (const u32x4*)fw1f;
    u32x4* d4 = (u32x4*)W1s;
    d4[tid] = s4[tid];
    d4[tid+256] = s4[tid+256];
  }
  __syncthreads();

  float fb2v[8];
  #pragma unroll
  for(int t=0;t<8;t++) fb2v[t] = ldin(fb2,(size_t)iidx*128 + t*16+l15,isbf);
  float aggp[8];
  #pragma unroll
  for(int t=0;t<8;t++) aggp[t]=0.f;

  const float width = 5.0f/24.0f;
  const float coeff = -0.5f/(width*width);

  for(int mt=0; mt<4; mt++){
    asm volatile("s_waitcnt lgkmcnt(0)" ::: "memory");   // prev-mt H reads done
    float r    = R [(size_t)atom*64 + mt*16 + l15];
    float cm_l = CM[(size_t)atom*64 + mt*16 + l15];
    float ln2cm  = 0.69314718f*cm_l;
    // gaussian B-frag (k=25 -> 1.0 bias slot)
    float gv[8];
    #pragma unroll
    for(int j=0;j<8;j++){
      int k = q*8+j;
      if(k < 25){ float t = fmaf(-width,(float)k,r); gv[j] = __expf(coeff*t*t); }
      else gv[j] = (k==25) ? 1.f : 0.f;
    }
    union{ u32 d[4]; bf16x8 v; } afu;
    afu.d[0]=pk2(gv[0],gv[1]); afu.d[1]=pk2(gv[2],gv[3]);
    afu.d[2]=pk2(gv[4],gv[5]); afu.d[3]=pk2(gv[6],gv[7]);
    bf16x8 af = afu.v;

    // S1': Ht = fw1^T @ f^T  (lane holds H[nbr=l15][filt=t*16+q*4+r], bias incl.)
    f32x4 acc[8];
    #pragma unroll
    for(int t=0;t<8;t++){
      bf16x8 w1 = *(const bf16x8*)(W1s + t*512 + lane*8);
      acc[t] = mfma16(w1, af, (f32x4){0.f,0.f,0.f,0.f});
    }
    // h = cm * ssp(x);  pack pairs; one b64 write per t
    #pragma unroll
    for(int t=0;t<8;t++){
      float h0 = fmaf(__logf(1.f+__expf(acc[t][0])), cm_l, -ln2cm);
      float h1 = fmaf(__logf(1.f+__expf(acc[t][1])), cm_l, -ln2cm);
      float h2 = fmaf(__logf(1.f+__expf(acc[t][2])), cm_l, -ln2cm);
      float h3 = fmaf(__logf(1.f+__expf(acc[t][3])), cm_l, -ln2cm);
      u32x2 d; d[0]=pk2(h0,h1); d[1]=pk2(h2,h3);
      *(u32x2*)(&H[l15][t*16 + q*4]) = d;
    }
    asm volatile("s_waitcnt lgkmcnt(0)" ::: "memory");   // writes visible

    // S2: (C·H) @ fw2
    #pragma unroll
    for(int t=0;t<8;t++) acc[t] = (f32x4){0.f,0.f,0.f,0.f};
    #pragma unroll
    for(int kk=0;kk<4;kk++){
      bf16x8 a2 = *(const bf16x8*)(&H[l15][kk*32 + q*8]);
      #pragma unroll
      for(int t=0;t<8;t++){
        bf16x8 wv = *(const bf16x8*)(fw2f + ((kk*8+t)*64 + lane)*8);
        acc[t] = mfma16(a2, wv, acc[t]);
      }
    }
    // epilogue: agg += (acc + fb2*cm) * y[nbr]
    f32x4 cmv = *(const f32x4*)(CM + (size_t)atom*64 + mt*16 + q*4);
    int4  nb4 = *(const int4*)(nbrs + (size_t)atom*64 + mt*16 + q*4);
    #pragma unroll
    for(int t=0;t<8;t++){
      int col = t*16 + l15;
      float w0 = fmaf(fb2v[t], cmv[0], acc[t][0]);
      float w1 = fmaf(fb2v[t], cmv[1], acc[t][1]);
      float w2 = fmaf(fb2v[t], cmv[2], acc[t][2]);
      float w3 = fmaf(fb2v[t], cmv[3], acc[t][3]);
      aggp[t] = fmaf(w0, Y[(size_t)(bbase+nb4.x)*128+col], aggp[t]);
      aggp[t] = fmaf(w1, Y[(size_t)(bbase+nb4.y)*128+col], aggp[t]);
      aggp[t] = fmaf(w2, Y[(size_t)(bbase+nb4.z)*128+col], aggp[t]);
      aggp[t] = fmaf(w3, Y[(size_t)(bbase+nb4.w)*128+col], aggp[t]);
    }
  }
  #pragma unroll
  for(int t=0;t<8;t++){
    float v = aggp[t];
    v += __shfl_xor(v, 16, 64);
    v += __shfl_xor(v, 32, 64);
    aggp[t] = v;
  }
  if(q==0){
    #pragma unroll
    for(int t=0;t<8;t++) AGG[(size_t)atom*128 + t*16 + l15] = aggp[t];
  }
}

// ---------------------------------------------------------------------------
// v = ssp(agg @ f2out + b) @ dense + b;  x += v;  (if !last) y = x @ in2f_next
// All three GEMMs transposed -> b64 LDS writes, b128 reads, float4 X/Y stores.
__global__ __launch_bounds__(256) void k_out(const float* __restrict__ AGG,
                                             float* __restrict__ X,
                                             float* __restrict__ Y,
                                             const u16* __restrict__ f2of,
                                             const u16* __restrict__ denf,
                                             const u16* __restrict__ in2fN,
                                             const void* __restrict__ f2ob,
                                             const void* __restrict__ denb,
                                             const void* __restrict__ nmask,
                                             void* __restrict__ OUT,
                                             int last, int iidx){
  __shared__ __align__(16) u16 Tb[4][16][136];
  __shared__ __align__(16) u16 Xb[4][16][136];
  int isbf = probe_bf(nmask);
  int widx = threadIdx.x>>6;
  int lane = threadIdx.x & 63;
  int q = lane>>4, l15 = lane&15;
  int row0 = (blockIdx.x*4 + widx)*16;
  u16 (*T)[136]  = Tb[widx];
  u16 (*Xw)[136] = Xb[widx];

  // G1': T^T = f2o^T @ agg^T, then ssp(+bias)
  f32x4 acc[8];
  #pragma unroll
  for(int t=0;t<8;t++) acc[t] = (f32x4){0.f,0.f,0.f,0.f};
  #pragma unroll
  for(int kk=0;kk<4;kk++){
    bf16x8 gf = ldfragA_f32(AGG + (size_t)(row0+l15)*128 + kk*32 + q*8);
    #pragma unroll
    for(int t=0;t<8;t++){
      bf16x8 wv = *(const bf16x8*)(f2of + ((kk*8+t)*64 + lane)*8);
      acc[t] = mfma16(wv, gf, acc[t]);       // D[col t*16+q*4+r][row l15]
    }
  }
  #pragma unroll
  for(int t=0;t<8;t++){
    f32x4 bv = ldin4(f2ob, (size_t)iidx*128 + t*16 + q*4, isbf);
    u32x2 d;
    d[0] = pk2(sspf(acc[t][0]+bv[0]), sspf(acc[t][1]+bv[1]));
    d[1] = pk2(sspf(acc[t][2]+bv[2]), sspf(acc[t][3]+bv[3]));
    *(u32x2*)(&T[l15][t*16 + q*4]) = d;
  }
  asm volatile("s_waitcnt lgkmcnt(0)" ::: "memory");

  // G2': dense^T @ T^T + bias + X (residual)
  #pragma unroll
  for(int t=0;t<8;t++) acc[t] = (f32x4){0.f,0.f,0.f,0.f};
  #pragma unroll
  for(int kk=0;kk<4;kk++){
    bf16x8 tf = *(const bf16x8*)(&T[l15][kk*32 + q*8]);
    #pragma unroll
    for(int t=0;t<8;t++){
      bf16x8 wv = *(const bf16x8*)(denf + ((kk*8+t)*64 + lane)*8);
      acc[t] = mfma16(wv, tf, acc[t]);
    }
  }
  #pragma unroll
  for(int t=0;t<8;t++){
    size_t idx = (size_t)(row0+l15)*128 + t*16 + q*4;
    f32x4 bv = ldin4(denb, (size_t)iidx*128 + t*16 + q*4, isbf);
    f32x4 xv = *(const f32x4*)(X + idx);
    f32x4 xn;
    #pragma unroll
    for(int r=0;r<4;r++) xn[r] = xv[r] + acc[t][r] + bv[r];
    *(f32x4*)(X + idx) = xn;
    if(last){
      if(isbf){
        u32x2 o; o[0]=pk2(xn[0],xn[1]); o[1]=pk2(xn[2],xn[3]);
        *(u32x2*)((u16*)OUT + idx) = o;
      } else {
        *(f32x4*)((float*)OUT + idx) = xn;
      }
    } else {
      u32x2 d; d[0]=pk2(xn[0],xn[1]); d[1]=pk2(xn[2],xn[3]);
      *(u32x2*)(&Xw[l15][t*16 + q*4]) = d;
    }
  }
  if(!last){
    asm volatile("s_waitcnt lgkmcnt(0)" ::: "memory");
    // G3': y^T = in2f^T @ xnew^T  -> float4 Y stores
    #pragma unroll
    for(int t=0;t<8;t++) acc[t] = (f32x4){0.f,0.f,0.f,0.f};
    #pragma unroll
    for(int kk=0;kk<4;kk++){
      bf16x8 xf = *(const bf16x8*)(&Xw[l15][kk*32 + q*8]);
      #pragma unroll
      for(int t=0;t<8;t++){
        bf16x8 wv = *(const bf16x8*)(in2fN + ((kk*8+t)*64 + lane)*8);
        acc[t] = mfma16(wv, xf, acc[t]);
      }
    }
    #pragma unroll
    for(int t=0;t<8;t++)
      *(f32x4*)(Y + (size_t)(row0+l15)*128 + t*16 + q*4) = acc[t];
  }
}

// ---------------------------------------------------------------------------
extern "C" void kernel_launch(void* const* d_in, const int* in_sizes, int n_in,
                              void* d_out, int out_size, void* d_ws, size_t ws_size,
                              hipStream_t stream){
  const void* pos   = d_in[0];
  const void* cell  = d_in[1];
  const void* cello = d_in[2];
  const void* nmask = d_in[3];
  // d_in[4] atom_mask: unused by the output
  const void* emb   = d_in[5];
  const void* fw1   = d_in[6];
  const void* fb1   = d_in[7];
  const void* fw2   = d_in[8];
  const void* fb2   = d_in[9];
  const void* in2f  = d_in[10];
  const void* f2o   = d_in[11];
  const void* f2ob  = d_in[12];
  const void* den   = d_in[13];
  const void* denb  = d_in[14];
  const int* z      = (const int*)d_in[15];
  const int* nbrs   = (const int*)d_in[16];

  char* ws = (char*)d_ws;
  float* X   = (float*)(ws);                 //  4 MB fp32 features
  float* Y   = (float*)(ws +  4194304);      //  4 MB projected features
  float* AGG = (float*)(ws +  8388608);      //  4 MB cfconv aggregate
  float* R   = (float*)(ws + 12582912);      //  2 MB distances
  float* CMp = (float*)(ws + 14680064);      //  2 MB cutoff*mask
  u16*   WF  = (u16*)  (ws + 16777216);      // 408 KB weight B-frags

  k_setup<<<6246, 256, 0, stream>>>(pos, cell, cello, nmask, emb,
                                    fw1, fb1, fw2, in2f, f2o, den,
                                    z, nbrs, X, R, CMp, WF);
  k_proj <<< 128, 256, 0, stream>>>(X, WF + 20480, Y);

  for(int i=0;i<3;i++){
    const u16* base = WF + (size_t)i*69632;
    k_cfconv<<<2048, 256, 0, stream>>>(R, CMp, Y, nbrs,
                                       base + 0      /* fw1 frags (k=25 bias) */,
                                       base + 4096   /* fw2 frags */,
                                       fb2, nmask, AGG, i);
    const u16* in2fN = (i<2) ? (WF + (size_t)(i+1)*69632 + 20480) : WF;
    k_out<<<128, 256, 0, stream>>>(AGG, X, Y,
                                   base + 36864 /* f2out frags */,
                                   base + 53248 /* dense frags */,
                                   in2fN,
                                   f2ob, denb, nmask,
                                   d_out, (i==2) ? 1 : 0, i);
  }
}

// Round 7
// 306.860 us; speedup vs baseline: 2.4726x; 1.2235x over previous
//
#include <hip/hip_runtime.h>

typedef __attribute__((ext_vector_type(8))) short bf16x8;
typedef __attribute__((ext_vector_type(4))) float f32x4;
typedef __attribute__((ext_vector_type(2))) unsigned int u32x2;
typedef __attribute__((ext_vector_type(4))) unsigned int u32x4;
typedef __attribute__((ext_vector_type(2))) __bf16 bf16x2t;
typedef unsigned short u16;
typedef unsigned int u32;

#define DI __device__ __forceinline__

// Problem constants: B=8, A=1024, NB=64, NAB=NF=128, NG=25, NI=3

DI float b2f(u16 u){ union{u32 i; float f;} v; v.i = ((u32)u)<<16; return v.f; }
DI u16 f2b(float f){ union{float f; u32 i;} v; v.f=f; u32 u=v.i;
                     return (u16)((u + 0x7fffu + ((u>>16)&1u))>>16); }
// packed 2xf32 -> 2xbf16; lo = low 16 bits.  v_cvt_pk_bf16_f32 when available.
DI u32 pk2(float lo, float hi){
#if __has_builtin(__builtin_amdgcn_cvt_pk_bf16_f32)
  bf16x2t h = __builtin_amdgcn_cvt_pk_bf16_f32(lo, hi);
  u32 d; __builtin_memcpy(&d, &h, 4); return d;
#else
  return (u32)f2b(lo) | ((u32)f2b(hi)<<16);
#endif
}
// native exp2/log2 (single v_exp_f32 / v_log_f32)
DI float fexp2(float x){
#if __has_builtin(__builtin_amdgcn_exp2f)
  return __builtin_amdgcn_exp2f(x);
#else
  return __expf(x*0.6931471805599453f);
#endif
}
DI float flog2(float x){
#if __has_builtin(__builtin_amdgcn_logf)
  return __builtin_amdgcn_logf(x);
#else
  return __logf(x)*1.4426950408889634f;
#endif
}
// dtype-agnostic input load (element index): isbf ? bf16 : f32
DI float ldin(const void* p, size_t i, int isbf){
  return isbf ? b2f(((const u16*)p)[i]) : ((const float*)p)[i];
}
// 4 consecutive elements (i % 4 == 0)
DI f32x4 ldin4(const void* p, size_t i, int isbf){
  if(isbf){
    u32x2 d = *(const u32x2*)((const u16*)p + i);
    f32x4 r;
    r[0] = b2f((u16)(d[0]&0xffff)); r[1] = b2f((u16)(d[0]>>16));
    r[2] = b2f((u16)(d[1]&0xffff)); r[3] = b2f((u16)(d[1]>>16));
    return r;
  }
  return *(const f32x4*)((const float*)p + i);
}
DI int probe_bf(const void* nmask){ return ((const u16*)nmask)[0] == 0x3F80u; }

DI f32x4 mfma16(bf16x8 a, bf16x8 b, f32x4 c){
  return __builtin_amdgcn_mfma_f32_16x16x32_bf16(a,b,c,0,0,0);
}
// fragment (8 consecutive k as bf16) from fp32 global memory
DI bf16x8 ldfragA_f32(const float* p){
  f32x4 a = ((const f32x4*)p)[0], b = ((const f32x4*)p)[1];
  union{ u32 d[4]; bf16x8 v; } u;
  u.d[0]=pk2(a[0],a[1]); u.d[1]=pk2(a[2],a[3]);
  u.d[2]=pk2(b[0],b[1]); u.d[3]=pk2(b[2],b[3]);
  return u.v;
}
DI float sspf(float x){            // ssp = log(1+e^x) - ln2  (|x| << 80 guaranteed)
  return __logf(1.f + __expf(x)) - 0.6931471805599453f;
}

// ---------------------------------------------------------------------------
// Fused setup: blocks [0,4096) embed | [4096,6144) dist | [6144,6246) wfrag
// fw1 (and its k=25 bias row) are pre-scaled by log2e so k_cfconv's S1
// accumulator is already x*log2e (exp2 domain).
__global__ __launch_bounds__(256) void k_setup(const void* __restrict__ pos,
                                               const void* __restrict__ cell,
                                               const void* __restrict__ cello,
                                               const void* __restrict__ nmask,
                                               const void* __restrict__ emb,
                                               const void* __restrict__ fw1,
                                               const void* __restrict__ fb1,
                                               const void* __restrict__ fw2,
                                               const void* __restrict__ in2f,
                                               const void* __restrict__ f2o,
                                               const void* __restrict__ den,
                                               const int* __restrict__ z,
                                               const int* __restrict__ nbrs,
                                               float* __restrict__ X,
                                               float* __restrict__ R,
                                               float* __restrict__ CM,
                                               u16* __restrict__ WF){
  int isbf = probe_bf(nmask);
  int bx = blockIdx.x, tid = threadIdx.x;
  if(bx < 4096){
    int idx = bx*256 + tid;                    // < 8192*128
    int a = idx>>7, f = idx&127;
    X[idx] = ldin(emb, (size_t)z[a]*128 + f, isbf);
    return;
  }
  if(bx < 6144){
    int pairIdx = (bx-4096)*256 + tid;         // < 8192*64
    int atom = pairIdx>>6;
    int b = atom>>10;
    int nb = nbrs[pairIdx];
    int jrow = (b<<10) + nb;
    float pi0=ldin(pos,atom*3+0,isbf), pi1=ldin(pos,atom*3+1,isbf), pi2=ldin(pos,atom*3+2,isbf);
    float pj0=ldin(pos,jrow*3+0,isbf), pj1=ldin(pos,jrow*3+1,isbf), pj2=ldin(pos,jrow*3+2,isbf);
    float co0=ldin(cello,(size_t)pairIdx*3+0,isbf),
          co1=ldin(cello,(size_t)pairIdx*3+1,isbf),
          co2=ldin(cello,(size_t)pairIdx*3+2,isbf);
    size_t cb = (size_t)b*9;
    pj0 += co0*ldin(cell,cb+0,isbf) + co1*ldin(cell,cb+3,isbf) + co2*ldin(cell,cb+6,isbf);
    pj1 += co0*ldin(cell,cb+1,isbf) + co1*ldin(cell,cb+4,isbf) + co2*ldin(cell,cb+7,isbf);
    pj2 += co0*ldin(cell,cb+2,isbf) + co1*ldin(cell,cb+5,isbf) + co2*ldin(cell,cb+8,isbf);
    float d0 = pj0-pi0, d1 = pj1-pi1, d2 = pj2-pi2;
    float dd = d0*d0 + d1*d1 + d2*d2;
    float m  = ldin(nmask,pairIdx,isbf);
    float r  = sqrtf(m>0.f ? dd : 1.f) * m;
    R[pairIdx] = r;
    float c = 0.5f*(__cosf(r*3.14159265358979f/5.f)+1.f) * ((r<5.f)?1.f:0.f) * m;
    CM[pairIdx] = c;
    return;
  }
  // weight fragments: wid in [0,408) = 3 interactions x 136 frags
  int wid = (bx-6144)*4 + (tid>>6);
  int lane = tid & 63;
  int q = lane>>4, l15 = lane&15;
  int i = wid/136, r = wid%136;
  int mat, kk, t;
  if(r < 8){ mat=0; kk=0; t=r; }
  else { int r2 = r-8; mat = 1 + (r2>>5); kk = (r2>>3)&3; t = r2&7; }
  const void* src; size_t sbase; int K; int off;
  switch(mat){
    case 0:  src = fw1;  sbase=(size_t)i*3200;  K=25;  off=0;     break;
    case 1:  src = fw2;  sbase=(size_t)i*16384; K=128; off=4096;  break;
    case 2:  src = in2f; sbase=(size_t)i*16384; K=128; off=20480; break;
    case 3:  src = f2o;  sbase=(size_t)i*16384; K=128; off=36864; break;
    default: src = den;  sbase=(size_t)i*16384; K=128; off=53248; break;
  }
  int c = t*16 + l15;
  bf16x8 frag;
  #pragma unroll
  for(int j=0;j<8;j++){
    int k = kk*32 + q*8 + j;
    float v;
    if(k < K)                 v = ldin(src, sbase + (size_t)k*128 + c, isbf);
    else if(mat==0 && k==25)  v = ldin(fb1, (size_t)i*128 + c, isbf);   // bias row
    else                      v = 0.f;
    if(mat==0) v *= 1.4426950408889634f;       // log2e pre-scale (exp2 domain)
    frag[j] = (short)f2b(v);
  }
  *(bf16x8*)(WF + (size_t)i*69632 + off + ((kk*8+t)*64 + lane)*8) = frag;
}

// ---------------------------------------------------------------------------
// y = x @ in2f (iteration 0).  One wave per block -> 512 blocks (full GPU).
__global__ __launch_bounds__(64) void k_proj(const float* __restrict__ X,
                                             const u16* __restrict__ wf,
                                             float* __restrict__ Y){
  int wid = blockIdx.x;                        // tile id < 512
  int lane = threadIdx.x;
  int q = lane>>4, l15 = lane&15;
  int row0 = wid*16;
  f32x4 acc[8];
  #pragma unroll
  for(int t=0;t<8;t++) acc[t] = (f32x4){0.f,0.f,0.f,0.f};
  #pragma unroll
  for(int kk=0;kk<4;kk++){
    bf16x8 xf = ldfragA_f32(X + (size_t)(row0+l15)*128 + kk*32 + q*8);
    #pragma unroll
    for(int t=0;t<8;t++){
      bf16x8 wv = *(const bf16x8*)(wf + ((kk*8+t)*64 + lane)*8);
      acc[t] = mfma16(wv, xf, acc[t]);        // transposed: D[col t*16+q*4+r][row l15]
    }
  }
  #pragma unroll
  for(int t=0;t<8;t++)
    *(f32x4*)(Y + (size_t)(row0+l15)*128 + t*16 + q*4) = acc[t];
}

// ---------------------------------------------------------------------------
// CFConv: ONE BLOCK PER ATOM, each of the 4 waves owns one neighbor m-tile.
// Serial chain per wave is 1 m-tile (R6 had 4 + 8 LDS drains); partial aggs
// reduced through LDS.  ssp in exp2/log2 domain (fw1 pre-scaled by log2e):
//   h = cm*ln2 * (log2(1+2^acc) - 1)
// No explicit lgkmcnt fences: H tile is written+read by the same wave and
// DS ops from one wave execute in order.
// NOTE (R4/R5 lesson): gfx950 unified VGPR/AGPR file — do NOT add a
// min-waves arg to __launch_bounds__ (it forces a split -> scratch spills).
__global__ __launch_bounds__(256) void k_cfconv(const float* __restrict__ R,
                                                const float* __restrict__ CM,
                                                const float* __restrict__ Y,
                                                const int* __restrict__ nbrs,
                                                const u16* __restrict__ fw1f,
                                                const u16* __restrict__ fw2f,
                                                const void* __restrict__ fb2,
                                                const void* __restrict__ nmask,
                                                float* __restrict__ AGG,
                                                int iidx){
  __shared__ __align__(16) u16 W1s[4096];          // 8 KB fw1 frags (block-shared)
  __shared__ __align__(16) u16 Hb[4][16][136];     // 17 KB per-wave H tiles
  __shared__ float Red[4][128];                    // 2 KB partial aggs
  int isbf = probe_bf(nmask);
  int tid = threadIdx.x;
  int mt  = tid>>6;                 // wave index == m-tile index
  int lane = tid & 63;
  int q = lane>>4, l15 = lane&15;
  int atom = blockIdx.x;
  int bbase = atom & ~1023;
  u16 (*H)[136] = Hb[mt];

  { // stage fw1 frags: 8192 B cooperative copy
    const u32x4* s4 = (const u32x4*)fw1f;
    u32x4* d4 = (u32x4*)W1s;
    d4[tid] = s4[tid];
    d4[tid+256] = s4[tid+256];
  }
  __syncthreads();

  float fb2v[8];
  #pragma unroll
  for(int t=0;t<8;t++) fb2v[t] = ldin(fb2,(size_t)iidx*128 + t*16+l15,isbf);

  const float width = 5.0f/24.0f;
  const float c2 = (-0.5f/(width*width))*1.4426950408889634f;  // coeff*log2e
  float r    = R [(size_t)atom*64 + mt*16 + l15];
  float cm_l = CM[(size_t)atom*64 + mt*16 + l15];
  float cmln2 = 0.69314718055994531f*cm_l;

  // gaussian B-frag in exp2 domain (k=25 -> 1.0 bias slot)
  float gv[8];
  #pragma unroll
  for(int j=0;j<8;j++){
    int k = q*8+j;
    if(k < 25){ float t = fmaf(-width,(float)k,r); gv[j] = fexp2(c2*t*t); }
    else gv[j] = (k==25) ? 1.f : 0.f;
  }
  union{ u32 d[4]; bf16x8 v; } afu;
  afu.d[0]=pk2(gv[0],gv[1]); afu.d[1]=pk2(gv[2],gv[3]);
  afu.d[2]=pk2(gv[4],gv[5]); afu.d[3]=pk2(gv[6],gv[7]);
  bf16x8 af = afu.v;

  // S1': acc = (fw1*log2e)^T @ f^T   (lane holds x*log2e for H[l15][t*16+q*4+r])
  f32x4 acc[8];
  #pragma unroll
  for(int t=0;t<8;t++){
    bf16x8 w1 = *(const bf16x8*)(W1s + t*512 + lane*8);
    acc[t] = mfma16(w1, af, (f32x4){0.f,0.f,0.f,0.f});
  }
  // h = cmln2*(log2(1+2^acc) - 1);  pack pairs; one b64 write per t
  #pragma unroll
  for(int t=0;t<8;t++){
    float h0 = fmaf(flog2(1.f+fexp2(acc[t][0])), cmln2, -cmln2);
    float h1 = fmaf(flog2(1.f+fexp2(acc[t][1])), cmln2, -cmln2);
    float h2 = fmaf(flog2(1.f+fexp2(acc[t][2])), cmln2, -cmln2);
    float h3 = fmaf(flog2(1.f+fexp2(acc[t][3])), cmln2, -cmln2);
    u32x2 d; d[0]=pk2(h0,h1); d[1]=pk2(h2,h3);
    *(u32x2*)(&H[l15][t*16 + q*4]) = d;
  }

  // S2: (C·H) @ fw2   (same-wave DS ordering makes H reads safe)
  #pragma unroll
  for(int t=0;t<8;t++) acc[t] = (f32x4){0.f,0.f,0.f,0.f};
  #pragma unroll
  for(int kk=0;kk<4;kk++){
    bf16x8 a2 = *(const bf16x8*)(&H[l15][kk*32 + q*8]);
    #pragma unroll
    for(int t=0;t<8;t++){
      bf16x8 wv = *(const bf16x8*)(fw2f + ((kk*8+t)*64 + lane)*8);
      acc[t] = mfma16(a2, wv, acc[t]);
    }
  }
  // epilogue: aggp += (acc + fb2*cm) * y[nbr]
  float aggp[8];
  #pragma unroll
  for(int t=0;t<8;t++) aggp[t]=0.f;
  f32x4 cmv = *(const f32x4*)(CM + (size_t)atom*64 + mt*16 + q*4);
  int4  nb4 = *(const int4*)(nbrs + (size_t)atom*64 + mt*16 + q*4);
  #pragma unroll
  for(int t=0;t<8;t++){
    int col = t*16 + l15;
    float w0 = fmaf(fb2v[t], cmv[0], acc[t][0]);
    float w1 = fmaf(fb2v[t], cmv[1], acc[t][1]);
    float w2 = fmaf(fb2v[t], cmv[2], acc[t][2]);
    float w3 = fmaf(fb2v[t], cmv[3], acc[t][3]);
    aggp[t] = fmaf(w0, Y[(size_t)(bbase+nb4.x)*128+col], aggp[t]);
    aggp[t] = fmaf(w1, Y[(size_t)(bbase+nb4.y)*128+col], aggp[t]);
    aggp[t] = fmaf(w2, Y[(size_t)(bbase+nb4.z)*128+col], aggp[t]);
    aggp[t] = fmaf(w3, Y[(size_t)(bbase+nb4.w)*128+col], aggp[t]);
  }
  // intra-wave q-reduce, then cross-wave reduce via LDS
  #pragma unroll
  for(int t=0;t<8;t++){
    float v = aggp[t];
    v += __shfl_xor(v, 16, 64);
    v += __shfl_xor(v, 32, 64);
    aggp[t] = v;
  }
  if(q==0){
    #pragma unroll
    for(int t=0;t<8;t++) Red[mt][t*16 + l15] = aggp[t];
  }
  __syncthreads();
  if(tid < 128){
    float s = Red[0][tid] + Red[1][tid] + Red[2][tid] + Red[3][tid];
    AGG[(size_t)atom*128 + tid] = s;
  }
}

// ---------------------------------------------------------------------------
// v = ssp(agg @ f2out + b) @ dense + b;  x += v;  (if !last) y = x @ in2f_next
// One wave per block -> 512 blocks (R6 used 128 blocks = half the CUs idle).
__global__ __launch_bounds__(64) void k_out(const float* __restrict__ AGG,
                                            float* __restrict__ X,
                                            float* __restrict__ Y,
                                            const u16* __restrict__ f2of,
                                            const u16* __restrict__ denf,
                                            const u16* __restrict__ in2fN,
                                            const void* __restrict__ f2ob,
                                            const void* __restrict__ denb,
                                            const void* __restrict__ nmask,
                                            void* __restrict__ OUT,
                                            int last, int iidx){
  __shared__ __align__(16) u16 T[16][136];
  __shared__ __align__(16) u16 Xw[16][136];
  int isbf = probe_bf(nmask);
  int lane = threadIdx.x;
  int q = lane>>4, l15 = lane&15;
  int row0 = blockIdx.x*16;

  // G1': T^T = f2o^T @ agg^T, then ssp(+bias)
  f32x4 acc[8];
  #pragma unroll
  for(int t=0;t<8;t++) acc[t] = (f32x4){0.f,0.f,0.f,0.f};
  #pragma unroll
  for(int kk=0;kk<4;kk++){
    bf16x8 gf = ldfragA_f32(AGG + (size_t)(row0+l15)*128 + kk*32 + q*8);
    #pragma unroll
    for(int t=0;t<8;t++){
      bf16x8 wv = *(const bf16x8*)(f2of + ((kk*8+t)*64 + lane)*8);
      acc[t] = mfma16(wv, gf, acc[t]);       // D[col t*16+q*4+r][row l15]
    }
  }
  #pragma unroll
  for(int t=0;t<8;t++){
    f32x4 bv = ldin4(f2ob, (size_t)iidx*128 + t*16 + q*4, isbf);
    u32x2 d;
    d[0] = pk2(sspf(acc[t][0]+bv[0]), sspf(acc[t][1]+bv[1]));
    d[1] = pk2(sspf(acc[t][2]+bv[2]), sspf(acc[t][3]+bv[3]));
    *(u32x2*)(&T[l15][t*16 + q*4]) = d;
  }

  // G2': dense^T @ T^T + bias + X (residual)   (same-wave DS ordering)
  #pragma unroll
  for(int t=0;t<8;t++) acc[t] = (f32x4){0.f,0.f,0.f,0.f};
  #pragma unroll
  for(int kk=0;kk<4;kk++){
    bf16x8 tf = *(const bf16x8*)(&T[l15][kk*32 + q*8]);
    #pragma unroll
    for(int t=0;t<8;t++){
      bf16x8 wv = *(const bf16x8*)(denf + ((kk*8+t)*64 + lane)*8);
      acc[t] = mfma16(wv, tf, acc[t]);
    }
  }
  #pragma unroll
  for(int t=0;t<8;t++){
    size_t idx = (size_t)(row0+l15)*128 + t*16 + q*4;
    f32x4 bv = ldin4(denb, (size_t)iidx*128 + t*16 + q*4, isbf);
    f32x4 xv = *(const f32x4*)(X + idx);
    f32x4 xn;
    #pragma unroll
    for(int r=0;r<4;r++) xn[r] = xv[r] + acc[t][r] + bv[r];
    *(f32x4*)(X + idx) = xn;
    if(last){
      if(isbf){
        u32x2 o; o[0]=pk2(xn[0],xn[1]); o[1]=pk2(xn[2],xn[3]);
        *(u32x2*)((u16*)OUT + idx) = o;
      } else {
        *(f32x4*)((float*)OUT + idx) = xn;
      }
    } else {
      u32x2 d; d[0]=pk2(xn[0],xn[1]); d[1]=pk2(xn[2],xn[3]);
      *(u32x2*)(&Xw[l15][t*16 + q*4]) = d;
    }
  }
  if(!last){
    // G3': y^T = in2f^T @ xnew^T  -> float4 Y stores
    #pragma unroll
    for(int t=0;t<8;t++) acc[t] = (f32x4){0.f,0.f,0.f,0.f};
    #pragma unroll
    for(int kk=0;kk<4;kk++){
      bf16x8 xf = *(const bf16x8*)(&Xw[l15][kk*32 + q*8]);
      #pragma unroll
      for(int t=0;t<8;t++){
        bf16x8 wv = *(const bf16x8*)(in2fN + ((kk*8+t)*64 + lane)*8);
        acc[t] = mfma16(wv, xf, acc[t]);
      }
    }
    #pragma unroll
    for(int t=0;t<8;t++)
      *(f32x4*)(Y + (size_t)(row0+l15)*128 + t*16 + q*4) = acc[t];
  }
}

// ---------------------------------------------------------------------------
extern "C" void kernel_launch(void* const* d_in, const int* in_sizes, int n_in,
                              void* d_out, int out_size, void* d_ws, size_t ws_size,
                              hipStream_t stream){
  const void* pos   = d_in[0];
  const void* cell  = d_in[1];
  const void* cello = d_in[2];
  const void* nmask = d_in[3];
  // d_in[4] atom_mask: unused by the output
  const void* emb   = d_in[5];
  const void* fw1   = d_in[6];
  const void* fb1   = d_in[7];
  const void* fw2   = d_in[8];
  const void* fb2   = d_in[9];
  const void* in2f  = d_in[10];
  const void* f2o   = d_in[11];
  const void* f2ob  = d_in[12];
  const void* den   = d_in[13];
  const void* denb  = d_in[14];
  const int* z      = (const int*)d_in[15];
  const int* nbrs   = (const int*)d_in[16];

  char* ws = (char*)d_ws;
  float* X   = (float*)(ws);                 //  4 MB fp32 features
  float* Y   = (float*)(ws +  4194304);      //  4 MB projected features
  float* AGG = (float*)(ws +  8388608);      //  4 MB cfconv aggregate
  float* R   = (float*)(ws + 12582912);      //  2 MB distances
  float* CMp = (float*)(ws + 14680064);      //  2 MB cutoff*mask
  u16*   WF  = (u16*)  (ws + 16777216);      // 408 KB weight B-frags

  k_setup<<<6246, 256, 0, stream>>>(pos, cell, cello, nmask, emb,
                                    fw1, fb1, fw2, in2f, f2o, den,
                                    z, nbrs, X, R, CMp, WF);
  k_proj <<< 512,  64, 0, stream>>>(X, WF + 20480, Y);

  for(int i=0;i<3;i++){
    const u16* base = WF + (size_t)i*69632;
    k_cfconv<<<8192, 256, 0, stream>>>(R, CMp, Y, nbrs,
                                       base + 0      /* fw1 frags (k=25 bias, log2e-scaled) */,
                                       base + 4096   /* fw2 frags */,
                                       fb2, nmask, AGG, i);
    const u16* in2fN = (i<2) ? (WF + (size_t)(i+1)*69632 + 20480) : WF;
    k_out<<<512, 64, 0, stream>>>(AGG, X, Y,
                                  base + 36864 /* f2out frags */,
                                  base + 53248 /* dense frags */,
                                  in2fN,
                                  f2ob, denb, nmask,
                                  d_out, (i==2) ? 1 : 0, i);
  }
}